// Round 1
// baseline (11421.082 us; speedup 1.0000x reference)
//
#include <hip/hip_runtime.h>
#include <math.h>

// Problem constants
#define T_  4
#define B_  8
#define C0  2
#define C1  128    // stem output channels (E/2)
#define C2  256    // main/residual output channels (E)
#define H_  128
#define W_  128
#define HP  130    // padded
#define WP  130
#define BN_EPS 1e-5f

// Spike workspace layout: uint8 [B][C1][HP][WP][T_]  (t innermost, one dword per (b,c,h,w))
// size = 8*128*130*130*4 = 69,222,400 bytes

__global__ __launch_bounds__(256) void zero_ws_kernel(uint4* __restrict__ p, int n16) {
    int i = blockIdx.x * 256 + threadIdx.x;
    int stride = gridDim.x * 256;
    for (; i < n16; i += stride) p[i] = make_uint4(0u, 0u, 0u, 0u);
}

// Stem: conv3x3 (C0=2 -> C1=128) + BN + LIF over T. One thread per (b,c,h,w).
__global__ __launch_bounds__(256) void stem_kernel(
    const float* __restrict__ x,   // [T,B,C0,H,W]
    const float* __restrict__ w0,  // [C1,C0,3,3]
    const float* __restrict__ g0, const float* __restrict__ b0,
    const float* __restrict__ m0, const float* __restrict__ v0,
    unsigned char* __restrict__ sp)
{
    const int c  = blockIdx.x;            // 0..127
    const int hb = blockIdx.y;            // 0..63
    const int b  = blockIdx.z;            // 0..7
    const int w  = threadIdx.x & 127;
    const int h  = hb * 2 + (threadIdx.x >> 7);

    // weights + BN params (wave-uniform: indexed by blockIdx only)
    float wt[C0][3][3];
#pragma unroll
    for (int ci = 0; ci < C0; ci++)
#pragma unroll
        for (int kh = 0; kh < 3; kh++)
#pragma unroll
            for (int kw = 0; kw < 3; kw++)
                wt[ci][kh][kw] = w0[((c * C0 + ci) * 3 + kh) * 3 + kw];

    const float inv = 1.0f / sqrtf(v0[c] + BN_EPS);
    const float sc  = g0[c] * inv;        // matches ref: (x-m)*(g*inv)+b
    const float mm  = m0[c];
    const float bb  = b0[c];

    float v = 0.0f;
    unsigned int pack = 0u;
#pragma unroll
    for (int t = 0; t < T_; t++) {
        const float* xb = x + (size_t)(t * B_ + b) * C0 * H_ * W_;
        float sum = 0.0f;
#pragma unroll
        for (int ci = 0; ci < C0; ci++) {
#pragma unroll
            for (int kh = 0; kh < 3; kh++) {
                const int hh = h + kh - 1;
                const bool hok = (unsigned)hh < (unsigned)H_;
#pragma unroll
                for (int kw = 0; kw < 3; kw++) {
                    const int ww = w + kw - 1;
                    const bool ok = hok && ((unsigned)ww < (unsigned)W_);
                    float xv = ok ? xb[(ci * H_ + hh) * W_ + ww] : 0.0f;
                    sum += xv * wt[ci][kh][kw];
                }
            }
        }
        const float y = (sum - mm) * sc + bb;   // BN
        v = v + (y - v) * 0.5f;                  // v += (x - v)/TAU, TAU=2
        const bool s = (v - 1.0f) >= 0.0f;       // Heaviside(v - V_TH)
        if (s) v = 0.0f;                         // hard reset
        pack |= (s ? 1u : 0u) << (8 * t);
    }
    const int idx = ((b * C1 + c) * HP + (h + 1)) * WP + (w + 1);
    *((unsigned int*)sp + idx) = pack;
}

// Fused main: conv3x3(C1->C2)+BN+LIF (z)  and  conv1x1(C1->C2)+BN+LIF (r), out = z + r.
// Block: 256 threads = 64 w-lanes x 4 co-groups. Thread owns 8 co x 4 t accs per branch.
// Grid: x = co_blk(8)*2 + w_blk(2), y = h(128), z = b(8).
#define CI_CHUNK 4
__global__ __launch_bounds__(256) void main_kernel(
    const unsigned char* __restrict__ sp,
    const float* __restrict__ w1,  // [C2,C1,3,3]
    const float* __restrict__ g1, const float* __restrict__ b1,
    const float* __restrict__ m1, const float* __restrict__ v1,
    const float* __restrict__ wr,  // [C2,C1,1,1]
    const float* __restrict__ gr, const float* __restrict__ br,
    const float* __restrict__ mr, const float* __restrict__ vr,
    float* __restrict__ out)       // [T,B,C2,H,W]
{
    const int w_blk  = blockIdx.x & 1;
    const int co_blk = blockIdx.x >> 1;   // 0..7 (32 co per block)
    const int h      = blockIdx.y;
    const int b      = blockIdx.z;
    const int lane   = threadIdx.x & 63;
    const int g      = threadIdx.x >> 6;  // 0..3
    const int w      = w_blk * 64 + lane;
    const int co_base = co_blk * 32 + g * 8;

    __shared__ __align__(16) float wlds[CI_CHUNK][32][12]; // 9 taps padded to 12
    __shared__ float wrlds[CI_CHUNK][32];

    float accZ[8][4];
    float accR[8][4];
#pragma unroll
    for (int i = 0; i < 8; i++)
#pragma unroll
        for (int t = 0; t < 4; t++) { accZ[i][t] = 0.0f; accR[i][t] = 0.0f; }

    const unsigned int* sprow = (const unsigned int*)sp;
    const int spbase = (b * C1) * HP * WP + h * WP + w;   // + ci*HP*WP + kh*WP + kw

    for (int ci0 = 0; ci0 < C1; ci0 += CI_CHUNK) {
        __syncthreads();   // previous chunk's reads complete
        // stage weights: CI_CHUNK * 32 co * 9 taps
        for (int f = threadIdx.x; f < CI_CHUNK * 32 * 9; f += 256) {
            const int cin = f / 288;
            const int rem = f - cin * 288;
            const int cl  = rem / 9;
            const int tap = rem - cl * 9;
            wlds[cin][cl][tap] = w1[((co_blk * 32 + cl) * C1 + (ci0 + cin)) * 9 + tap];
        }
        if (threadIdx.x < CI_CHUNK * 32) {
            const int cin = threadIdx.x >> 5;
            const int cl  = threadIdx.x & 31;
            wrlds[cin][cl] = wr[(co_blk * 32 + cl) * C1 + (ci0 + cin)];
        }
        __syncthreads();

#pragma unroll
        for (int cin = 0; cin < CI_CHUNK; cin++) {
            const int ci = ci0 + cin;
            // load spikes: 9 dwords, each holds 4 timesteps
            unsigned int d[3][3];
            const int rb = spbase + ci * (HP * WP);
#pragma unroll
            for (int kh = 0; kh < 3; kh++)
#pragma unroll
                for (int kw = 0; kw < 3; kw++)
                    d[kh][kw] = sprow[rb + kh * WP + kw];

            float s[3][3][4];
#pragma unroll
            for (int kh = 0; kh < 3; kh++)
#pragma unroll
                for (int kw = 0; kw < 3; kw++)
#pragma unroll
                    for (int t = 0; t < 4; t++)
                        s[kh][kw][t] = (float)((d[kh][kw] >> (8 * t)) & 0xffu);

#pragma unroll
            for (int cl = 0; cl < 8; cl++) {
                const float* wp = &wlds[cin][g * 8 + cl][0];
                const float4 wa = *(const float4*)(wp);      // taps 0-3
                const float4 wb = *(const float4*)(wp + 4);  // taps 4-7
                const float w22 = wp[8];
                const float wc  = wrlds[cin][g * 8 + cl];
#pragma unroll
                for (int t = 0; t < 4; t++) {
                    float a = accZ[cl][t];
                    a += s[0][0][t] * wa.x;
                    a += s[0][1][t] * wa.y;
                    a += s[0][2][t] * wa.z;
                    a += s[1][0][t] * wa.w;
                    a += s[1][1][t] * wb.x;
                    a += s[1][2][t] * wb.y;
                    a += s[2][0][t] * wb.z;
                    a += s[2][1][t] * wb.w;
                    a += s[2][2][t] * w22;
                    accZ[cl][t] = a;
                    accR[cl][t] += s[1][1][t] * wc;
                }
            }
        }
    }

    // Epilogue: BN + LIF per branch, out = z_spike + r_spike
#pragma unroll
    for (int cl = 0; cl < 8; cl++) {
        const int co = co_base + cl;
        const float sc1 = g1[co] * (1.0f / sqrtf(v1[co] + BN_EPS));
        const float scr = gr[co] * (1.0f / sqrtf(vr[co] + BN_EPS));
        const float m1v = m1[co], b1v = b1[co];
        const float mrv = mr[co], brv = br[co];
        float vz = 0.0f, vr_ = 0.0f;
#pragma unroll
        for (int t = 0; t < 4; t++) {
            const float yz = (accZ[cl][t] - m1v) * sc1 + b1v;
            vz = vz + (yz - vz) * 0.5f;
            const float sz = ((vz - 1.0f) >= 0.0f) ? 1.0f : 0.0f;
            if (sz != 0.0f) vz = 0.0f;

            const float yr = (accR[cl][t] - mrv) * scr + brv;
            vr_ = vr_ + (yr - vr_) * 0.5f;
            const float sr = ((vr_ - 1.0f) >= 0.0f) ? 1.0f : 0.0f;
            if (sr != 0.0f) vr_ = 0.0f;

            out[((size_t)(t * B_ + b) * C2 + co) * (H_ * W_) + h * W_ + w] = sz + sr;
        }
    }
}

extern "C" void kernel_launch(void* const* d_in, const int* in_sizes, int n_in,
                              void* d_out, int out_size, void* d_ws, size_t ws_size,
                              hipStream_t stream) {
    const float* x  = (const float*)d_in[0];
    const float* w0 = (const float*)d_in[1];
    const float* g0 = (const float*)d_in[2];
    const float* b0 = (const float*)d_in[3];
    const float* m0 = (const float*)d_in[4];
    const float* v0 = (const float*)d_in[5];
    const float* w1 = (const float*)d_in[6];
    const float* g1 = (const float*)d_in[7];
    const float* b1 = (const float*)d_in[8];
    const float* m1 = (const float*)d_in[9];
    const float* v1 = (const float*)d_in[10];
    const float* wr = (const float*)d_in[11];
    const float* gr = (const float*)d_in[12];
    const float* br = (const float*)d_in[13];
    const float* mr = (const float*)d_in[14];
    const float* vr = (const float*)d_in[15];

    unsigned char* sp = (unsigned char*)d_ws;
    const int n16 = (B_ * C1 * HP * WP * 4) / 16;   // uint4 count

    zero_ws_kernel<<<dim3(2048), dim3(256), 0, stream>>>((uint4*)sp, n16);
    stem_kernel<<<dim3(C1, H_ / 2, B_), dim3(256), 0, stream>>>(x, w0, g0, b0, m0, v0, sp);
    main_kernel<<<dim3(16, H_, B_), dim3(256), 0, stream>>>(
        sp, w1, g1, b1, m1, v1, wr, gr, br, mr, vr, (float*)d_out);
}

// Round 2
// 2868.038 us; speedup vs baseline: 3.9822x; 3.9822x over previous
//
#include <hip/hip_runtime.h>
#include <hip/hip_bf16.h>
#include <math.h>

#define T_  4
#define B_  8
#define C0  2
#define C1  128
#define C2  256
#define H_  128
#define W_  128
#define BN_EPS 1e-5f

// ---- workspace layout (total ~18.6 MB) ----
// sp: packed spikes, uint8 [B][130][130][128], bits0-3 = t0..t3
#define SP_OFF   0ull
#define SP_SIZE  17305600ull             // 8*130*130*128
#define AZHI_OFF (SP_OFF + SP_SIZE)
#define AZ_SIZE  589824ull               // 16cf * 144kq * 16r * 8j * 2B
#define AZLO_OFF (AZHI_OFF + AZ_SIZE)
#define ARHI_OFF (AZLO_OFF + AZ_SIZE)
#define AR_SIZE  65536ull                // 16cf * 16kq * 16r * 8j * 2B
#define ARLO_OFF (ARHI_OFF + AR_SIZE)
#define SC1_OFF  (ARLO_OFF + AR_SIZE)
#define SCR_OFF  (SC1_OFF + 1024ull)

typedef __attribute__((ext_vector_type(8))) short bf16x8;
typedef __attribute__((ext_vector_type(4))) float f32x4;

__device__ inline unsigned short f2bf(float f) {
    __hip_bfloat16 h = __float2bfloat16(f);
    return *reinterpret_cast<unsigned short*>(&h);
}
__device__ inline float bf2f(unsigned short u) {
    __hip_bfloat16 h;
    *reinterpret_cast<unsigned short*>(&h) = u;
    return __bfloat162float(h);
}

__global__ __launch_bounds__(256) void zero_ws_kernel(uint4* __restrict__ p, int n16) {
    int i = blockIdx.x * 256 + threadIdx.x;
    int stride = gridDim.x * 256;
    for (; i < n16; i += stride) p[i] = make_uint4(0u, 0u, 0u, 0u);
}

// Split weights into bf16 hi/lo, prepacked into MFMA A-fragment order.
// k (z-branch) = tap*128 + ci ; A[cf][kq][co&15][j], kq=k>>3, j=k&7.
__global__ __launch_bounds__(256) void prep_kernel(
    const float* __restrict__ w1, const float* __restrict__ wr,
    const float* __restrict__ g1, const float* __restrict__ v1,
    const float* __restrict__ gr, const float* __restrict__ vr,
    unsigned char* __restrict__ ws)
{
    const int tid = blockIdx.x * 256 + threadIdx.x;
    unsigned short* azhi = (unsigned short*)(ws + AZHI_OFF);
    unsigned short* azlo = (unsigned short*)(ws + AZLO_OFF);
    unsigned short* arhi = (unsigned short*)(ws + ARHI_OFF);
    unsigned short* arlo = (unsigned short*)(ws + ARLO_OFF);
    float* sc1 = (float*)(ws + SC1_OFF);
    float* scr = (float*)(ws + SCR_OFF);
    if (tid < 294912) {
        const int co = tid / 1152;
        const int k  = tid - co * 1152;
        const int tap = k >> 7;
        const int ci  = k & 127;
        const float val = w1[(co * 128 + ci) * 9 + tap];
        const unsigned short hi = f2bf(val);
        const unsigned short lo = f2bf(val - bf2f(hi));
        const int cf = co >> 4, r = co & 15, kq = k >> 3, j = k & 7;
        const int idx = ((cf * 144 + kq) * 16 + r) * 8 + j;
        azhi[idx] = hi; azlo[idx] = lo;
    } else if (tid < 327680) {
        const int e = tid - 294912;
        const int co = e >> 7, ci = e & 127;
        const float val = wr[co * 128 + ci];
        const unsigned short hi = f2bf(val);
        const unsigned short lo = f2bf(val - bf2f(hi));
        const int cf = co >> 4, r = co & 15, kq = ci >> 3, j = ci & 7;
        const int idx = ((cf * 16 + kq) * 16 + r) * 8 + j;
        arhi[idx] = hi; arlo[idx] = lo;
    } else if (tid < 327936) {
        const int c = tid - 327680;
        sc1[c] = g1[c] * (1.0f / sqrtf(v1[c] + BN_EPS));
        scr[c] = gr[c] * (1.0f / sqrtf(vr[c] + BN_EPS));
    }
}

// Stem: conv3x3 (2->128) + BN + LIF. Block = 64 w-lanes x 4 c-groups; thread
// loops 32 output channels reusing its x-neighborhood held in registers.
// Writes byte-packed spikes sp[b][h+1][w+1][c] (bits 0..3 = t).
__global__ __launch_bounds__(256) void stem_kernel(
    const float* __restrict__ x, const float* __restrict__ w0,
    const float* __restrict__ g0, const float* __restrict__ b0,
    const float* __restrict__ m0, const float* __restrict__ v0,
    unsigned char* __restrict__ sp)
{
    const int wseg = blockIdx.x;   // 0..1
    const int h    = blockIdx.y;   // 0..127
    const int b    = blockIdx.z;   // 0..7
    const int lane = threadIdx.x & 63;
    const int cg   = threadIdx.x >> 6;   // 0..3
    const int w    = wseg * 64 + lane;

    __shared__ float wl[2304];           // [c][ci*9+tap]
    __shared__ float sc0s[128], m0s[128], b0s[128];

    for (int i = threadIdx.x; i < 2304; i += 256) wl[i] = w0[i];
    if (threadIdx.x < 128) {
        const int c = threadIdx.x;
        sc0s[c] = g0[c] * (1.0f / sqrtf(v0[c] + BN_EPS));
        m0s[c] = m0[c]; b0s[c] = b0[c];
    }
    __syncthreads();

    float xv[4][2][3][3];
#pragma unroll
    for (int t = 0; t < 4; ++t)
#pragma unroll
        for (int ci = 0; ci < 2; ++ci)
#pragma unroll
            for (int dh = 0; dh < 3; ++dh)
#pragma unroll
                for (int dw = 0; dw < 3; ++dw) {
                    const int hh = h + dh - 1, ww = w + dw - 1;
                    const bool ok = ((unsigned)hh < 128u) && ((unsigned)ww < 128u);
                    xv[t][ci][dh][dw] = ok ? x[(((size_t)(t * 8 + b) * 2 + ci) * 128 + hh) * 128 + ww] : 0.0f;
                }

    unsigned char* dst = sp + (((size_t)(b * 130 + h + 1) * 130 + (w + 1)) * 128 + cg * 32);
    for (int i = 0; i < 8; ++i) {        // 8 dwords of 4 channels each
        unsigned dwv = 0u;
#pragma unroll
        for (int j = 0; j < 4; ++j) {
            const int c = cg * 32 + i * 4 + j;
            float wreg[18];
#pragma unroll
            for (int k = 0; k < 18; ++k) wreg[k] = wl[c * 18 + k];
            const float sc = sc0s[c], mm = m0s[c], bb = b0s[c];
            float v = 0.0f; unsigned bits = 0u;
#pragma unroll
            for (int t = 0; t < 4; ++t) {
                float sum = 0.0f;
#pragma unroll
                for (int ci = 0; ci < 2; ++ci)
#pragma unroll
                    for (int dh = 0; dh < 3; ++dh)
#pragma unroll
                        for (int dw = 0; dw < 3; ++dw)
                            sum += xv[t][ci][dh][dw] * wreg[ci * 9 + dh * 3 + dw];
                const float y = (sum - mm) * sc + bb;
                v = v + (y - v) * 0.5f;
                if (v - 1.0f >= 0.0f) { bits |= 1u << t; v = 0.0f; }
            }
            dwv |= bits << (j * 8);
        }
        *(unsigned*)(dst + i * 4) = dwv;
    }
}

// Fused main: conv3x3(z) + conv1x1(r), both +BN+LIF, out = z_spike + r_spike.
// Implicit GEMM via mfma_f32_16x16x32_bf16, split-bf16 weights (hi+lo).
// Block 256 thr = 4 waves; wave = 32 co x (16 pix x 4 t x 2 h-rows).
// Grid (wseg 8, hseg 8, b*2+coblk 16). LDS spike tile conflict-free:
// [4 rows][4 t][16 ciq][18 pix][8 ci] bf16 = 73728 B -> 2 blocks/CU.
__global__ __launch_bounds__(256, 2) void main_mfma(
    const unsigned char* __restrict__ ws,
    const float* __restrict__ m1, const float* __restrict__ b1,
    const float* __restrict__ mr, const float* __restrict__ br,
    float* __restrict__ out)
{
    const int wseg = blockIdx.x;
    const int hseg = blockIdx.y;
    const int b    = blockIdx.z >> 1;
    const int coblk= blockIdx.z & 1;
    const int tid  = threadIdx.x;
    const int lane = tid & 63;
    const int wid  = tid >> 6;
    const int q    = lane >> 4;
    const int r16  = lane & 15;
    const int wbase = wseg * 16;
    const int hbase = hseg * 16;

    __shared__ short tile[36864];

    const unsigned char* sp = ws;
    const char* AzhiB = (const char*)(ws + AZHI_OFF);
    const char* AzloB = (const char*)(ws + AZLO_OFF);
    const char* ArhiB = (const char*)(ws + ARHI_OFF);
    const char* ArloB = (const char*)(ws + ARLO_OFF);
    const float* sc1 = (const float*)(ws + SC1_OFF);
    const float* scr = (const float*)(ws + SCR_OFF);

    const int baseB = q * 288 + r16 * 16;   // LDS byte base within (row,t,cq)
    const int baseA = q * 256 + r16 * 16;   // A byte base within (cf,kq-block)
    const int cfg0  = coblk * 8 + wid * 2;

    auto decode_row = [&](int R) {
        const int phys = R & 3;
        for (int u = tid; u < 288; u += 256) {
            const int ciq = u & 15;
            const int pix = u >> 4;
            const unsigned char* p = sp + (((size_t)(b * 130 + R) * 130 + (wbase + pix)) * 128 + ciq * 8);
            const uint2 dd = *(const uint2*)p;
#pragma unroll
            for (int t = 0; t < 4; ++t) {
                const unsigned ma = (dd.x >> t) & 0x01010101u;
                const unsigned mb = (dd.y >> t) & 0x01010101u;
                uint4 o;
                o.x = (ma & 1u) * 0x3F80u + (ma & 0x100u) * 0x3F8000u;
                o.y = ((ma >> 16) & 1u) * 0x3F80u + ((ma >> 16) & 0x100u) * 0x3F8000u;
                o.z = (mb & 1u) * 0x3F80u + (mb & 0x100u) * 0x3F8000u;
                o.w = ((mb >> 16) & 1u) * 0x3F80u + ((mb >> 16) & 0x100u) * 0x3F8000u;
                *(uint4*)&tile[(((phys * 4 + t) * 16 + ciq) * 18 + pix) * 8] = o;
            }
        }
    };

    decode_row(hbase);
    decode_row(hbase + 1);

    for (int ppp = 0; ppp < 8; ++ppp) {
        const int h0 = hbase + 2 * ppp;
        __syncthreads();                  // prior pass's LDS reads complete
        decode_row(h0 + 2);
        decode_row(h0 + 3);
        __syncthreads();

        f32x4 accZ[2][4][2];
        f32x4 accR[2][4][2];
#pragma unroll
        for (int a = 0; a < 2; ++a)
#pragma unroll
            for (int t = 0; t < 4; ++t)
#pragma unroll
                for (int hh = 0; hh < 2; ++hh) {
                    accZ[a][t][hh] = (f32x4)(0.0f);
                    accR[a][t][hh] = (f32x4)(0.0f);
                }

        int prow[4];
#pragma unroll
        for (int k = 0; k < 4; ++k) prow[k] = ((h0 + k) & 3) * 18432;

#pragma unroll
        for (int kh = 0; kh < 3; ++kh) {
#pragma unroll
            for (int kw = 0; kw < 3; ++kw) {
                const int tap = kh * 3 + kw;
#pragma unroll
                for (int cq = 0; cq < 4; ++cq) {
                    bf16x8 bf[4][2];
#pragma unroll
                    for (int t = 0; t < 4; ++t) {
                        const int o = ((t * 16 + cq * 4) * 18 + kw) * 16 + baseB;
                        bf[t][0] = *(const bf16x8*)&tile[(prow[kh] + o) >> 1];
                        bf[t][1] = *(const bf16x8*)&tile[(prow[kh + 1] + o) >> 1];
                    }
                    const int kqb = (tap * 16 + cq * 4) * 256;
                    bf16x8 ah[2], al[2];
#pragma unroll
                    for (int cf = 0; cf < 2; ++cf) {
                        const int abyte = (cfg0 + cf) * 36864 + kqb + baseA;
                        ah[cf] = *(const bf16x8*)(AzhiB + abyte);
                        al[cf] = *(const bf16x8*)(AzloB + abyte);
                    }
#pragma unroll
                    for (int cf = 0; cf < 2; ++cf)
#pragma unroll
                        for (int t = 0; t < 4; ++t)
#pragma unroll
                            for (int hh = 0; hh < 2; ++hh) {
                                accZ[cf][t][hh] = __builtin_amdgcn_mfma_f32_16x16x32_bf16(ah[cf], bf[t][hh], accZ[cf][t][hh], 0, 0, 0);
                                accZ[cf][t][hh] = __builtin_amdgcn_mfma_f32_16x16x32_bf16(al[cf], bf[t][hh], accZ[cf][t][hh], 0, 0, 0);
                            }
                    if (tap == 4) {
                        bf16x8 rh[2], rl[2];
#pragma unroll
                        for (int cf = 0; cf < 2; ++cf) {
                            const int rbyte = (cfg0 + cf) * 4096 + cq * 1024 + baseA;
                            rh[cf] = *(const bf16x8*)(ArhiB + rbyte);
                            rl[cf] = *(const bf16x8*)(ArloB + rbyte);
                        }
#pragma unroll
                        for (int cf = 0; cf < 2; ++cf)
#pragma unroll
                            for (int t = 0; t < 4; ++t)
#pragma unroll
                                for (int hh = 0; hh < 2; ++hh) {
                                    accR[cf][t][hh] = __builtin_amdgcn_mfma_f32_16x16x32_bf16(rh[cf], bf[t][hh], accR[cf][t][hh], 0, 0, 0);
                                    accR[cf][t][hh] = __builtin_amdgcn_mfma_f32_16x16x32_bf16(rl[cf], bf[t][hh], accR[cf][t][hh], 0, 0, 0);
                                }
                    }
                }
            }
        }

        // Epilogue: BN + LIF (t-series is in-lane), out = z_spike + r_spike
        const int co_w = coblk * 128 + wid * 32;
#pragma unroll
        for (int cf = 0; cf < 2; ++cf)
#pragma unroll
            for (int reg = 0; reg < 4; ++reg) {
                const int co = co_w + cf * 16 + q * 4 + reg;
                const float s1 = sc1[co], mm1 = m1[co], bb1 = b1[co];
                const float s2 = scr[co], mm2 = mr[co], bb2 = br[co];
#pragma unroll
                for (int hh = 0; hh < 2; ++hh) {
                    float vz = 0.0f, vr2 = 0.0f;
                    float* op = out + (size_t)b * 4194304 + (size_t)co * 16384
                                    + (size_t)(h0 + hh) * 128 + (wbase + r16);
#pragma unroll
                    for (int t = 0; t < 4; ++t) {
                        const float yz = (accZ[cf][t][hh][reg] - mm1) * s1 + bb1;
                        vz = vz + (yz - vz) * 0.5f;
                        float sz = 0.0f;
                        if (vz - 1.0f >= 0.0f) { sz = 1.0f; vz = 0.0f; }
                        const float yr = (accR[cf][t][hh][reg] - mm2) * s2 + bb2;
                        vr2 = vr2 + (yr - vr2) * 0.5f;
                        float sr = 0.0f;
                        if (vr2 - 1.0f >= 0.0f) { sr = 1.0f; vr2 = 0.0f; }
                        op[(size_t)t * 33554432] = sz + sr;
                    }
                }
            }
    }
}

extern "C" void kernel_launch(void* const* d_in, const int* in_sizes, int n_in,
                              void* d_out, int out_size, void* d_ws, size_t ws_size,
                              hipStream_t stream) {
    const float* x  = (const float*)d_in[0];
    const float* w0 = (const float*)d_in[1];
    const float* g0 = (const float*)d_in[2];
    const float* b0 = (const float*)d_in[3];
    const float* m0 = (const float*)d_in[4];
    const float* v0 = (const float*)d_in[5];
    const float* w1 = (const float*)d_in[6];
    const float* g1 = (const float*)d_in[7];
    const float* b1 = (const float*)d_in[8];
    const float* m1 = (const float*)d_in[9];
    const float* v1 = (const float*)d_in[10];
    const float* wr = (const float*)d_in[11];
    const float* gr = (const float*)d_in[12];
    const float* br = (const float*)d_in[13];
    const float* mr = (const float*)d_in[14];
    const float* vr = (const float*)d_in[15];

    unsigned char* ws = (unsigned char*)d_ws;
    const int n16 = (int)(SP_SIZE / 16);

    zero_ws_kernel<<<dim3(2048), dim3(256), 0, stream>>>((uint4*)ws, n16);
    prep_kernel<<<dim3(1281), dim3(256), 0, stream>>>(w1, wr, g1, v1, gr, vr, ws);
    stem_kernel<<<dim3(2, 128, 8), dim3(256), 0, stream>>>(x, w0, g0, b0, m0, v0, ws + SP_OFF);
    main_mfma<<<dim3(8, 8, 16), dim3(256), 0, stream>>>(ws, m1, b1, mr, br, (float*)d_out);
}

// Round 3
// 1224.891 us; speedup vs baseline: 9.3242x; 2.3415x over previous
//
#include <hip/hip_runtime.h>
#include <hip/hip_bf16.h>
#include <math.h>

#define T_  4
#define B_  8
#define C0  2
#define C1  128
#define C2  256
#define H_  128
#define W_  128
#define BN_EPS 1e-5f

// ---- workspace layout ----
// sp: packed spikes, uint8 [B][130][130][128], bits0-3 = t0..t3
#define SP_OFF   0ull
#define SP_SIZE  17305600ull             // 8*130*130*128
#define AZHI_OFF (SP_OFF + SP_SIZE)
#define AZ_SIZE  589824ull               // 16cf * 144kq * 16r * 8j * 2B
#define AZLO_OFF (AZHI_OFF + AZ_SIZE)
#define ARHI_OFF (AZLO_OFF + AZ_SIZE)
#define AR_SIZE  65536ull                // 16cf * 16kq * 16r * 8j * 2B
#define ARLO_OFF (ARHI_OFF + AR_SIZE)
#define PRM_OFF  (ARLO_OFF + AR_SIZE)    // 1024 floats: zsc|zoff|rsc|roff

// ---- LDS layout for main kernel (148480 B total) ----
#define LDS_AZHI 0
#define LDS_AZLO 36864
#define LDS_ARHI 73728
#define LDS_ARLO 77824
#define LDS_SP   81920                   // 4 slots * 130 pix * 128 ci = 66560

typedef __attribute__((ext_vector_type(8))) short bf16x8;
typedef __attribute__((ext_vector_type(4))) float f32x4;

__device__ inline unsigned short f2bf(float f) {
    __hip_bfloat16 h = __float2bfloat16(f);
    return *reinterpret_cast<unsigned short*>(&h);
}
__device__ inline float bf2f(unsigned short u) {
    __hip_bfloat16 h;
    *reinterpret_cast<unsigned short*>(&h) = u;
    return __bfloat162float(h);
}
__device__ inline bf16x8 u4bf(uint4 u) {
    union { uint4 a; bf16x8 b; } c; c.a = u; return c.b;
}

#define MFMA16(acc, A, Bb) acc = __builtin_amdgcn_mfma_f32_16x16x32_bf16(A, Bb, acc, 0, 0, 0)

__global__ __launch_bounds__(256) void zero_ws_kernel(uint4* __restrict__ p, int n16) {
    int i = blockIdx.x * 256 + threadIdx.x;
    int stride = gridDim.x * 256;
    for (; i < n16; i += stride) p[i] = make_uint4(0u, 0u, 0u, 0u);
}

// Split weights into bf16 hi/lo, prepacked into MFMA A-fragment order.
// k (z-branch) = tap*128 + ci ; A[cf][kq][co&15][j], kq=k>>3, j=k&7.
__global__ __launch_bounds__(256) void prep_kernel(
    const float* __restrict__ w1, const float* __restrict__ wr,
    const float* __restrict__ g1, const float* __restrict__ v1,
    const float* __restrict__ b1, const float* __restrict__ m1,
    const float* __restrict__ gr, const float* __restrict__ vr,
    const float* __restrict__ br, const float* __restrict__ mr,
    unsigned char* __restrict__ ws)
{
    const int tid = blockIdx.x * 256 + threadIdx.x;
    unsigned short* azhi = (unsigned short*)(ws + AZHI_OFF);
    unsigned short* azlo = (unsigned short*)(ws + AZLO_OFF);
    unsigned short* arhi = (unsigned short*)(ws + ARHI_OFF);
    unsigned short* arlo = (unsigned short*)(ws + ARLO_OFF);
    float* prm = (float*)(ws + PRM_OFF);
    if (tid < 294912) {
        const int co = tid / 1152;
        const int k  = tid - co * 1152;
        const int tap = k >> 7;
        const int ci  = k & 127;
        const float val = w1[(co * 128 + ci) * 9 + tap];
        const unsigned short hi = f2bf(val);
        const unsigned short lo = f2bf(val - bf2f(hi));
        const int cf = co >> 4, r = co & 15, kq = k >> 3, j = k & 7;
        const int idx = ((cf * 144 + kq) * 16 + r) * 8 + j;
        azhi[idx] = hi; azlo[idx] = lo;
    } else if (tid < 327680) {
        const int e = tid - 294912;
        const int co = e >> 7, ci = e & 127;
        const float val = wr[co * 128 + ci];
        const unsigned short hi = f2bf(val);
        const unsigned short lo = f2bf(val - bf2f(hi));
        const int cf = co >> 4, r = co & 15, kq = ci >> 3, j = ci & 7;
        const int idx = ((cf * 16 + kq) * 16 + r) * 8 + j;
        arhi[idx] = hi; arlo[idx] = lo;
    } else if (tid < 327936) {
        const int c = tid - 327680;
        const float s1 = g1[c] * (1.0f / sqrtf(v1[c] + BN_EPS));
        const float s2 = gr[c] * (1.0f / sqrtf(vr[c] + BN_EPS));
        prm[c]        = s1;
        prm[256 + c]  = b1[c] - m1[c] * s1;
        prm[512 + c]  = s2;
        prm[768 + c]  = br[c] - mr[c] * s2;
    }
}

// Stem: conv3x3 (2->128) + BN + LIF, writes packed spikes sp[b][h+1][w+1][c].
__global__ __launch_bounds__(256) void stem_kernel(
    const float* __restrict__ x, const float* __restrict__ w0,
    const float* __restrict__ g0, const float* __restrict__ b0,
    const float* __restrict__ m0, const float* __restrict__ v0,
    unsigned char* __restrict__ sp)
{
    const int wseg = blockIdx.x;
    const int h    = blockIdx.y;
    const int b    = blockIdx.z;
    const int lane = threadIdx.x & 63;
    const int cg   = threadIdx.x >> 6;
    const int w    = wseg * 64 + lane;

    __shared__ float wl[2304];
    __shared__ float sc0s[128], m0s[128], b0s[128];

    for (int i = threadIdx.x; i < 2304; i += 256) wl[i] = w0[i];
    if (threadIdx.x < 128) {
        const int c = threadIdx.x;
        sc0s[c] = g0[c] * (1.0f / sqrtf(v0[c] + BN_EPS));
        m0s[c] = m0[c]; b0s[c] = b0[c];
    }
    __syncthreads();

    float xv[4][2][3][3];
#pragma unroll
    for (int t = 0; t < 4; ++t)
#pragma unroll
        for (int ci = 0; ci < 2; ++ci)
#pragma unroll
            for (int dh = 0; dh < 3; ++dh)
#pragma unroll
                for (int dw = 0; dw < 3; ++dw) {
                    const int hh = h + dh - 1, ww = w + dw - 1;
                    const bool ok = ((unsigned)hh < 128u) && ((unsigned)ww < 128u);
                    xv[t][ci][dh][dw] = ok ? x[(((size_t)(t * 8 + b) * 2 + ci) * 128 + hh) * 128 + ww] : 0.0f;
                }

    unsigned char* dst = sp + (((size_t)(b * 130 + h + 1) * 130 + (w + 1)) * 128 + cg * 32);
    for (int i = 0; i < 8; ++i) {
        unsigned dwv = 0u;
#pragma unroll
        for (int j = 0; j < 4; ++j) {
            const int c = cg * 32 + i * 4 + j;
            float wreg[18];
#pragma unroll
            for (int k = 0; k < 18; ++k) wreg[k] = wl[c * 18 + k];
            const float sc = sc0s[c], mm = m0s[c], bb = b0s[c];
            float v = 0.0f; unsigned bits = 0u;
#pragma unroll
            for (int t = 0; t < 4; ++t) {
                float sum = 0.0f;
#pragma unroll
                for (int ci = 0; ci < 2; ++ci)
#pragma unroll
                    for (int dh = 0; dh < 3; ++dh)
#pragma unroll
                        for (int dw = 0; dw < 3; ++dw)
                            sum += xv[t][ci][dh][dw] * wreg[ci * 9 + dh * 3 + dw];
                const float y = (sum - mm) * sc + bb;
                v = v + (y - v) * 0.5f;
                if (v - 1.0f >= 0.0f) { bits |= 1u << t; v = 0.0f; }
            }
            dwv |= bits << (j * 8);
        }
        *(unsigned*)(dst + i * 4) = dwv;
    }
}

// Main fused kernel. Block = 4 waves, covers 16 co x 128 w x 8 h-rows x 4 t.
// A (16 co, full K, hi+lo) persistent in LDS; spikes packed in a 4-row LDS
// ring (XOR-swizzled ci for conflict-free ds_read_b64); bf16 expand in VALU.
// Grid: (coblk 16, hstrip 16, b 8).
__global__ __launch_bounds__(256, 1) void main_mfma(
    const unsigned char* __restrict__ ws,
    float* __restrict__ out)
{
    __shared__ char lds[148480];

    const int coblk  = blockIdx.x;
    const int hstrip = blockIdx.y;
    const int b      = blockIdx.z;
    const int tid  = threadIdx.x;
    const int lane = tid & 63;
    const int wid  = tid >> 6;
    const int q    = lane >> 4;
    const int r16  = lane & 15;
    const int wbase  = wid * 32;
    const int hfirst = hstrip * 8;

    const unsigned char* spg = ws + SP_OFF;

    // ---- stage A slices + initial 4 spike rows ----
    {
        const unsigned char* s1 = ws + AZHI_OFF + (size_t)coblk * 36864;
        const unsigned char* s2 = ws + AZLO_OFF + (size_t)coblk * 36864;
        for (int i = tid; i < 2304; i += 256) {
            *(uint4*)&lds[LDS_AZHI + i * 16] = *(const uint4*)(s1 + i * 16);
            *(uint4*)&lds[LDS_AZLO + i * 16] = *(const uint4*)(s2 + i * 16);
        }
        const unsigned char* s3 = ws + ARHI_OFF + (size_t)coblk * 4096;
        const unsigned char* s4 = ws + ARLO_OFF + (size_t)coblk * 4096;
        if (tid < 256) {
            *(uint4*)&lds[LDS_ARHI + tid * 16] = *(const uint4*)(s3 + tid * 16);
            *(uint4*)&lds[LDS_ARLO + tid * 16] = *(const uint4*)(s4 + tid * 16);
        }
        for (int i = tid; i < 4160; i += 256) {           // 4 rows * 1040 uint4
            const int rr  = i / 1040;
            const int rem = i - rr * 1040;
            const int pix = rem >> 3;
            const int ch  = rem & 7;
            const int R = hfirst - 1 + rr;                 // -1..130 range ok
            const uint4 v = *(const uint4*)(spg + (((size_t)(b * 130) + (R + 1)) * 130 + pix) * 128 + ch * 16);
            const int slot = R & 3;
            *(uint4*)&lds[LDS_SP + (slot * 130 + pix) * 128 + ((ch * 16) ^ ((pix & 7) << 4))] = v;
        }
    }

    // BN params (folded): y = acc*sc + off
    const float* prm = (const float*)(ws + PRM_OFF);
    float zsc[4], zof[4], rsc[4], rof[4];
#pragma unroll
    for (int reg = 0; reg < 4; ++reg) {
        const int co = coblk * 16 + q * 4 + reg;
        zsc[reg] = prm[co];       zof[reg] = prm[256 + co];
        rsc[reg] = prm[512 + co]; rof[reg] = prm[768 + co];
    }
    __syncthreads();

    for (int p = 0; p < 4; ++p) {
        const int h0 = hfirst + 2 * p;

        // issue prefetch of next 2 rows into registers (latency hides under MFMA)
        uint4 pf[9];
        if (p < 3) {
            int k = 0;
            for (int i = tid; i < 2080; i += 256, ++k) {
                const int rr  = i / 1040;
                const int rem = i - rr * 1040;
                const int pix = rem >> 3;
                const int ch  = rem & 7;
                const int sprow = h0 + 4 + rr;
                pf[k] = *(const uint4*)(spg + (((size_t)(b * 130) + sprow) * 130 + pix) * 128 + ch * 16);
            }
        }

        f32x4 accZ[2][4][2];   // [nf][t][hh]
        f32x4 accR[2][4][2];
#pragma unroll
        for (int nf = 0; nf < 2; ++nf)
#pragma unroll
            for (int t = 0; t < 4; ++t)
#pragma unroll
                for (int hh = 0; hh < 2; ++hh) {
                    accZ[nf][t][hh] = (f32x4)(0.0f);
                    accR[nf][t][hh] = (f32x4)(0.0f);
                }

        for (int cq = 0; cq < 4; ++cq) {
#pragma unroll
            for (int kw = 0; kw < 3; ++kw) {
                // A fragments for 3 kh at this (cq,kw), hi+lo
                bf16x8 ah[3], al[3];
#pragma unroll
                for (int kh = 0; kh < 3; ++kh) {
                    const int abyte = (((kh * 3 + kw) * 16 + cq * 4 + q) * 256) + r16 * 16;
                    ah[kh] = *(const bf16x8*)&lds[LDS_AZHI + abyte];
                    al[kh] = *(const bf16x8*)&lds[LDS_AZLO + abyte];
                }
                bf16x8 rh, rl;
                if (kw == 1) {
                    const int rbyte = ((cq * 4 + q) * 256) + r16 * 16;
                    rh = *(const bf16x8*)&lds[LDS_ARHI + rbyte];
                    rl = *(const bf16x8*)&lds[LDS_ARLO + rbyte];
                }
#pragma unroll
                for (int rr = 0; rr < 4; ++rr) {
                    const int R = h0 - 1 + rr;
                    const int slot = R & 3;
#pragma unroll
                    for (int nf = 0; nf < 2; ++nf) {
                        const int pix = wbase + nf * 16 + r16 + kw;
                        const int cib = ((cq * 32 + (q >> 1) * 16) ^ ((pix & 7) << 4)) + (q & 1) * 8;
                        const uint2 d = *(const uint2*)&lds[LDS_SP + (slot * 130 + pix) * 128 + cib];
                        bf16x8 bf[4];
#pragma unroll
                        for (int t = 0; t < 4; ++t) {
                            const unsigned ma = (d.x >> t) & 0x01010101u;
                            const unsigned mb = (d.y >> t) & 0x01010101u;
                            uint4 o;
                            o.x = (ma & 1u) * 0x3F80u + (ma & 0x100u) * 0x3F8000u;
                            o.y = ((ma >> 16) & 1u) * 0x3F80u + ((ma >> 16) & 0x100u) * 0x3F8000u;
                            o.z = (mb & 1u) * 0x3F80u + (mb & 0x100u) * 0x3F8000u;
                            o.w = ((mb >> 16) & 1u) * 0x3F80u + ((mb >> 16) & 0x100u) * 0x3F8000u;
                            bf[t] = u4bf(o);
                        }
#pragma unroll
                        for (int t = 0; t < 4; ++t) {
                            if (rr <= 2) {         // hh=0, kh=rr
                                MFMA16(accZ[nf][t][0], ah[rr], bf[t]);
                                MFMA16(accZ[nf][t][0], al[rr], bf[t]);
                            }
                            if (rr >= 1) {         // hh=1, kh=rr-1
                                MFMA16(accZ[nf][t][1], ah[rr - 1], bf[t]);
                                MFMA16(accZ[nf][t][1], al[rr - 1], bf[t]);
                            }
                            if (kw == 1 && rr == 1) {
                                MFMA16(accR[nf][t][0], rh, bf[t]);
                                MFMA16(accR[nf][t][0], rl, bf[t]);
                            }
                            if (kw == 1 && rr == 2) {
                                MFMA16(accR[nf][t][1], rh, bf[t]);
                                MFMA16(accR[nf][t][1], rl, bf[t]);
                            }
                        }
                    }
                }
            }
        }

        __syncthreads();   // all LDS reads of this pass done

        if (p < 3) {       // commit prefetched rows (swizzled)
            int k = 0;
            for (int i = tid; i < 2080; i += 256, ++k) {
                const int rr  = i / 1040;
                const int rem = i - rr * 1040;
                const int pix = rem >> 3;
                const int ch  = rem & 7;
                const int R = h0 + 3 + rr;
                const int slot = R & 3;
                *(uint4*)&lds[LDS_SP + (slot * 130 + pix) * 128 + ((ch * 16) ^ ((pix & 7) << 4))] = pf[k];
            }
        }

        // Epilogue: BN + LIF both branches; out = z_spike + r_spike
#pragma unroll
        for (int nf = 0; nf < 2; ++nf)
#pragma unroll
            for (int reg = 0; reg < 4; ++reg) {
                const int co = coblk * 16 + q * 4 + reg;
#pragma unroll
                for (int hh = 0; hh < 2; ++hh) {
                    float vz = 0.0f, vr2 = 0.0f;
                    float* op = out + ((size_t)b * 256 + co) * 16384
                                    + (size_t)(h0 + hh) * 128 + wbase + nf * 16 + r16;
#pragma unroll
                    for (int t = 0; t < 4; ++t) {
                        const float yz = fmaf(accZ[nf][t][hh][reg], zsc[reg], zof[reg]);
                        vz = vz + (yz - vz) * 0.5f;
                        float sz = 0.0f;
                        if (vz - 1.0f >= 0.0f) { sz = 1.0f; vz = 0.0f; }
                        const float yr = fmaf(accR[nf][t][hh][reg], rsc[reg], rof[reg]);
                        vr2 = vr2 + (yr - vr2) * 0.5f;
                        float sr = 0.0f;
                        if (vr2 - 1.0f >= 0.0f) { sr = 1.0f; vr2 = 0.0f; }
                        op[(size_t)t * 33554432] = sz + sr;
                    }
                }
            }

        __syncthreads();   // new rows visible before next pass reads
    }
}

extern "C" void kernel_launch(void* const* d_in, const int* in_sizes, int n_in,
                              void* d_out, int out_size, void* d_ws, size_t ws_size,
                              hipStream_t stream) {
    const float* x  = (const float*)d_in[0];
    const float* w0 = (const float*)d_in[1];
    const float* g0 = (const float*)d_in[2];
    const float* b0 = (const float*)d_in[3];
    const float* m0 = (const float*)d_in[4];
    const float* v0 = (const float*)d_in[5];
    const float* w1 = (const float*)d_in[6];
    const float* g1 = (const float*)d_in[7];
    const float* b1 = (const float*)d_in[8];
    const float* m1 = (const float*)d_in[9];
    const float* v1 = (const float*)d_in[10];
    const float* wr = (const float*)d_in[11];
    const float* gr = (const float*)d_in[12];
    const float* br = (const float*)d_in[13];
    const float* mr = (const float*)d_in[14];
    const float* vr = (const float*)d_in[15];

    unsigned char* ws = (unsigned char*)d_ws;
    const int n16 = (int)(SP_SIZE / 16);

    zero_ws_kernel<<<dim3(2048), dim3(256), 0, stream>>>((uint4*)ws, n16);
    prep_kernel<<<dim3(1281), dim3(256), 0, stream>>>(w1, wr, g1, v1, b1, m1, gr, vr, br, mr, ws);
    stem_kernel<<<dim3(2, 128, 8), dim3(256), 0, stream>>>(x, w0, g0, b0, m0, v0, ws + SP_OFF);
    main_mfma<<<dim3(16, 16, 8), dim3(256), 0, stream>>>(ws, (float*)d_out);
}

// Round 4
// 670.351 us; speedup vs baseline: 17.0375x; 1.8272x over previous
//
#include <hip/hip_runtime.h>
#include <math.h>

#define T_  4
#define B_  8
#define C1  128
#define C2  256
#define H_  128
#define W_  128
#define BN_EPS 1e-5f

// ---- workspace layout ----
// sp: packed spikes uint8 [B][131 rows][130 pix][128 ci], bits0-3 = t0..t3,
//     byte offset within pixel block swizzled: c ^ ((pix&7)<<4)
#define SP_BSTR  2179840ull              // 131*130*128
#define SP_SIZE  17438720ull             // 8 * SP_BSTR
#define AZ0_OFF  SP_SIZE                 // 16coblk*9tap*2cq*1024 i8 digit0
#define AZ_SIZE  294912ull
#define AZ1_OFF  (AZ0_OFF + AZ_SIZE)
#define AR0_OFF  (AZ1_OFF + AZ_SIZE)     // 16coblk*2cq*1024
#define AR_SIZE  32768ull
#define AR1_OFF  (AR0_OFF + AR_SIZE)
#define PRM_OFF  (AR1_OFF + AR_SIZE)     // 1024 f32: zmul|zoff|rmul|roff

typedef __attribute__((ext_vector_type(4))) int i32x4;

#define MFI8(acc, A, Bv) acc = __builtin_amdgcn_mfma_i32_16x16x64_i8(A, Bv, acc, 0, 0, 0)

__global__ __launch_bounds__(256) void zero_ws_kernel(uint4* __restrict__ p, int n16) {
    int i = blockIdx.x * 256 + threadIdx.x;
    int stride = gridDim.x * 256;
    for (; i < n16; i += stride) p[i] = make_uint4(0u, 0u, 0u, 0u);
}

// Quantize weights to per-co 15-bit fixed point, split into 2 signed i8 digits,
// packed in MFMA A-fragment order (k = cq*64 + q*16 + j). Blocks 0-255: z (w1),
// blocks 256-511: r (wr). Also writes folded BN params.
__global__ __launch_bounds__(256) void prep_kernel(
    const float* __restrict__ w1, const float* __restrict__ wr,
    const float* __restrict__ g1, const float* __restrict__ v1,
    const float* __restrict__ b1, const float* __restrict__ m1,
    const float* __restrict__ gr, const float* __restrict__ vr,
    const float* __restrict__ br, const float* __restrict__ mr,
    unsigned char* __restrict__ ws)
{
    __shared__ float red[256];
    const int tid = threadIdx.x;
    const bool is_r = blockIdx.x >= 256;
    const int co = blockIdx.x & 255;
    const int n = is_r ? 128 : 1152;
    const float* wsrc = is_r ? (wr + co * 128) : (w1 + co * 1152);

    float mx = 0.0f;
    for (int i = tid; i < n; i += 256) mx = fmaxf(mx, fabsf(wsrc[i]));
    red[tid] = mx;
    __syncthreads();
    for (int s = 128; s > 0; s >>= 1) {
        if (tid < s) red[tid] = fmaxf(red[tid], red[tid + s]);
        __syncthreads();
    }
    const float scale = red[0];
    const float qs = 32638.0f / scale;

    char* d0p = (char*)(ws + (is_r ? AR0_OFF : AZ0_OFF));
    char* d1p = (char*)(ws + (is_r ? AR1_OFF : AZ1_OFF));
    for (int i = tid; i < n; i += 256) {
        const int wq = __float2int_rn(wsrc[i] * qs);
        const int d1 = ((wq + 128) & 255) - 128;
        const int d0 = (wq - d1) >> 8;
        int ci, tap;
        if (is_r) { ci = i; tap = 0; } else { ci = i / 9; tap = i - ci * 9; }
        const int cq = ci >> 6, qq = (ci >> 4) & 3, j = ci & 15;
        const int addr = is_r
            ? ((co >> 4) * 2048 + cq * 1024 + qq * 256 + (co & 15) * 16 + j)
            : ((co >> 4) * 18432 + (tap * 2 + cq) * 1024 + qq * 256 + (co & 15) * 16 + j);
        d0p[addr] = (char)d0;
        d1p[addr] = (char)d1;
    }
    if (tid == 0) {
        float* prm = (float*)(ws + PRM_OFF);
        if (!is_r) {
            const float s1 = g1[co] * (1.0f / sqrtf(v1[co] + BN_EPS));
            prm[co] = (scale / 32638.0f) * s1;
            prm[256 + co] = b1[co] - m1[co] * s1;
        } else {
            const float s2 = gr[co] * (1.0f / sqrtf(vr[co] + BN_EPS));
            prm[512 + co] = (scale / 32638.0f) * s2;
            prm[768 + co] = br[co] - mr[co] * s2;
        }
    }
}

// Stem: conv3x3 (2->128) + BN + LIF, writes packed (and byte-swizzled) spikes.
__global__ __launch_bounds__(256) void stem_kernel(
    const float* __restrict__ x, const float* __restrict__ w0,
    const float* __restrict__ g0, const float* __restrict__ b0,
    const float* __restrict__ m0, const float* __restrict__ v0,
    unsigned char* __restrict__ sp)
{
    const int wseg = blockIdx.x;
    const int h    = blockIdx.y;
    const int b    = blockIdx.z;
    const int lane = threadIdx.x & 63;
    const int cg   = threadIdx.x >> 6;
    const int w    = wseg * 64 + lane;

    __shared__ float wl[2304];
    __shared__ float sc0s[128], m0s[128], b0s[128];

    for (int i = threadIdx.x; i < 2304; i += 256) wl[i] = w0[i];
    if (threadIdx.x < 128) {
        const int c = threadIdx.x;
        sc0s[c] = g0[c] * (1.0f / sqrtf(v0[c] + BN_EPS));
        m0s[c] = m0[c]; b0s[c] = b0[c];
    }
    __syncthreads();

    float xv[4][2][3][3];
#pragma unroll
    for (int t = 0; t < 4; ++t)
#pragma unroll
        for (int ci = 0; ci < 2; ++ci)
#pragma unroll
            for (int dh = 0; dh < 3; ++dh)
#pragma unroll
                for (int dw = 0; dw < 3; ++dw) {
                    const int hh = h + dh - 1, ww = w + dw - 1;
                    const bool ok = ((unsigned)hh < 128u) && ((unsigned)ww < 128u);
                    xv[t][ci][dh][dw] = ok ? x[(((size_t)(t * 8 + b) * 2 + ci) * 128 + hh) * 128 + ww] : 0.0f;
                }

    const int pix = w + 1;
    const int sw = (pix & 7) << 4;
    unsigned char* dst = sp + ((size_t)b * SP_BSTR) + ((size_t)((h + 1) * 130 + pix)) * 128;
    for (int i = 0; i < 8; ++i) {
        unsigned dwv = 0u;
#pragma unroll
        for (int j = 0; j < 4; ++j) {
            const int c = cg * 32 + i * 4 + j;
            float wreg[18];
#pragma unroll
            for (int k = 0; k < 18; ++k) wreg[k] = wl[c * 18 + k];
            const float sc = sc0s[c], mm = m0s[c], bb = b0s[c];
            float v = 0.0f; unsigned bits = 0u;
#pragma unroll
            for (int t = 0; t < 4; ++t) {
                float sum = 0.0f;
#pragma unroll
                for (int ci = 0; ci < 2; ++ci)
#pragma unroll
                    for (int dh = 0; dh < 3; ++dh)
#pragma unroll
                        for (int dw = 0; dw < 3; ++dw)
                            sum += xv[t][ci][dh][dw] * wreg[ci * 9 + dh * 3 + dw];
                const float y = (sum - mm) * sc + bb;
                v = v + (y - v) * 0.5f;
                if (v - 1.0f >= 0.0f) { bits |= 1u << t; v = 0.0f; }
            }
            dwv |= bits << (j * 8);
        }
        *(unsigned*)(dst + ((cg * 32 + i * 4) ^ sw)) = dwv;
    }
}

// Main fused: conv3x3(z) + conv1x1(r) via mfma_i32_16x16x64_i8 (2 weight digits),
// BN + LIF both branches in-lane, out = z_spike + r_spike.
// Block = 4 waves = 16 co x 128 pix x 1 h-row x 4 t per pass, 8 passes.
// LDS = packed spike ring, 4 slots x 130 pix x 128 ci (65 KB) -> 2 blocks/CU.
// Grid: (coblk 16, hstrip 16, b 8).
__global__ __launch_bounds__(256, 2) void main_i8(
    const unsigned char* __restrict__ ws,
    float* __restrict__ out)
{
    __shared__ char ring[66560];   // 4 * 16640

    const int coblk  = blockIdx.x;
    const int hstrip = blockIdx.y;
    const int b      = blockIdx.z;
    const int tid  = threadIdx.x;
    const int lane = tid & 63;
    const int wid  = tid >> 6;
    const int q    = lane >> 4;
    const int r16  = lane & 15;
    const int wbase  = wid * 32;
    const int hfirst = hstrip * 8;

    const unsigned char* spg = ws;
    const char* Az0 = (const char*)(ws + AZ0_OFF) + coblk * 18432 + lane * 16;
    const char* Az1 = (const char*)(ws + AZ1_OFF) + coblk * 18432 + lane * 16;
    const char* Ar0 = (const char*)(ws + AR0_OFF) + coblk * 2048 + lane * 16;
    const char* Ar1 = (const char*)(ws + AR1_OFF) + coblk * 2048 + lane * 16;

    // folded epilogue params, per acc register (co = coblk*16 + q*4 + reg)
    const float* prm = (const float*)(ws + PRM_OFF);
    float zmul_[4], zoff_[4], rmul_[4], roff_[4];
#pragma unroll
    for (int reg = 0; reg < 4; ++reg) {
        const int co = coblk * 16 + q * 4 + reg;
        zmul_[reg] = prm[co];       zoff_[reg] = prm[256 + co];
        rmul_[reg] = prm[512 + co]; roff_[reg] = prm[768 + co];
    }

    // stage rows hfirst-1 .. hfirst+1 into slots (R+1)&3
    for (int i = tid; i < 3120; i += 256) {
        const int rr  = i / 1040;
        const int off = (i - rr * 1040) * 16;
        const int gr_ = hfirst + rr;          // global row = R+1
        const uint4 v = *(const uint4*)(spg + (size_t)b * SP_BSTR + (size_t)gr_ * 16640 + off);
        *(uint4*)&ring[(gr_ & 3) * 16640 + off] = v;
    }

    const unsigned M1 = 0x01010101u;

    for (int p = 0; p < 8; ++p) {
        const int h0 = hfirst + p;
        __syncthreads();   // prev pass LDS reads done; staged rows visible

        // prefetch next row (global row h0+3) into registers
        uint4 pf[5];
        if (p < 7) {
            const unsigned char* src = spg + (size_t)b * SP_BSTR + (size_t)(h0 + 3) * 16640;
#pragma unroll
            for (int it = 0; it < 5; ++it) {
                const int off = tid * 16 + it * 4096;
                if (off < 16640) pf[it] = *(const uint4*)(src + off);
            }
        }

        i32x4 z0[2][4], z1[2][4], r0[2][4], r1[2][4];
#pragma unroll
        for (int nf = 0; nf < 2; ++nf)
#pragma unroll
            for (int t = 0; t < 4; ++t) {
                z0[nf][t] = (i32x4)(0); z1[nf][t] = (i32x4)(0);
                r0[nf][t] = (i32x4)(0); r1[nf][t] = (i32x4)(0);
            }

#pragma unroll
        for (int cq = 0; cq < 2; ++cq) {
#pragma unroll
            for (int kw = 0; kw < 3; ++kw) {
                i32x4 a0[3], a1[3];
#pragma unroll
                for (int kh = 0; kh < 3; ++kh) {
                    const int fb = ((kh * 3 + kw) * 2 + cq) * 1024;
                    a0[kh] = *(const i32x4*)(Az0 + fb);
                    a1[kh] = *(const i32x4*)(Az1 + fb);
                }
                i32x4 c0, c1;
                if (kw == 1) {
                    c0 = *(const i32x4*)(Ar0 + cq * 1024);
                    c1 = *(const i32x4*)(Ar1 + cq * 1024);
                }
#pragma unroll
                for (int rr = 0; rr < 3; ++rr) {
                    const int slot = (h0 + rr) & 3;    // row h0-1+rr -> slot (R+1)&3
#pragma unroll
                    for (int nf = 0; nf < 2; ++nf) {
                        const int pix = wbase + nf * 16 + r16 + kw;
                        const int addr = slot * 16640 + pix * 128
                                       + ((cq * 64 + q * 16) ^ ((pix & 7) << 4));
                        const uint4 d = *(const uint4*)&ring[addr];
#pragma unroll
                        for (int t = 0; t < 4; ++t) {
                            i32x4 bt;
                            bt[0] = (int)((d.x >> t) & M1);
                            bt[1] = (int)((d.y >> t) & M1);
                            bt[2] = (int)((d.z >> t) & M1);
                            bt[3] = (int)((d.w >> t) & M1);
                            MFI8(z0[nf][t], a0[rr], bt);
                            MFI8(z1[nf][t], a1[rr], bt);
                            if (kw == 1 && rr == 1) {
                                MFI8(r0[nf][t], c0, bt);
                                MFI8(r1[nf][t], c1, bt);
                            }
                        }
                    }
                }
            }
        }

        // commit prefetched row (slot (h0+3)&3 — not read this pass)
        if (p < 7) {
            char* dst = &ring[((h0 + 3) & 3) * 16640];
#pragma unroll
            for (int it = 0; it < 5; ++it) {
                const int off = tid * 16 + it * 4096;
                if (off < 16640) *(uint4*)(dst + off) = pf[it];
            }
        }

        // Epilogue: combine digits, BN + LIF both branches, out = sz + sr
#pragma unroll
        for (int nf = 0; nf < 2; ++nf)
#pragma unroll
            for (int reg = 0; reg < 4; ++reg) {
                const int co = coblk * 16 + q * 4 + reg;
                float vz = 0.0f, vr2 = 0.0f;
                float* op = out + ((size_t)b * 256 + co) * 16384
                                + (size_t)h0 * 128 + wbase + nf * 16 + r16;
#pragma unroll
                for (int t = 0; t < 4; ++t) {
                    const int zi = z0[nf][t][reg] * 256 + z1[nf][t][reg];
                    const float yz = fmaf((float)zi, zmul_[reg], zoff_[reg]);
                    vz = vz + (yz - vz) * 0.5f;
                    float sz = 0.0f;
                    if (vz - 1.0f >= 0.0f) { sz = 1.0f; vz = 0.0f; }
                    const int ri = r0[nf][t][reg] * 256 + r1[nf][t][reg];
                    const float yr = fmaf((float)ri, rmul_[reg], roff_[reg]);
                    vr2 = vr2 + (yr - vr2) * 0.5f;
                    float sr = 0.0f;
                    if (vr2 - 1.0f >= 0.0f) { sr = 1.0f; vr2 = 0.0f; }
                    op[(size_t)t * 33554432] = sz + sr;
                }
            }
    }
}

extern "C" void kernel_launch(void* const* d_in, const int* in_sizes, int n_in,
                              void* d_out, int out_size, void* d_ws, size_t ws_size,
                              hipStream_t stream) {
    const float* x  = (const float*)d_in[0];
    const float* w0 = (const float*)d_in[1];
    const float* g0 = (const float*)d_in[2];
    const float* b0 = (const float*)d_in[3];
    const float* m0 = (const float*)d_in[4];
    const float* v0 = (const float*)d_in[5];
    const float* w1 = (const float*)d_in[6];
    const float* g1 = (const float*)d_in[7];
    const float* b1 = (const float*)d_in[8];
    const float* m1 = (const float*)d_in[9];
    const float* v1 = (const float*)d_in[10];
    const float* wr = (const float*)d_in[11];
    const float* gr = (const float*)d_in[12];
    const float* br = (const float*)d_in[13];
    const float* mr = (const float*)d_in[14];
    const float* vr = (const float*)d_in[15];

    unsigned char* ws = (unsigned char*)d_ws;
    const int n16 = (int)(SP_SIZE / 16);

    zero_ws_kernel<<<dim3(2048), dim3(256), 0, stream>>>((uint4*)ws, n16);
    prep_kernel<<<dim3(512), dim3(256), 0, stream>>>(w1, wr, g1, v1, b1, m1, gr, vr, br, mr, ws);
    stem_kernel<<<dim3(2, 128, 8), dim3(256), 0, stream>>>(x, w0, g0, b0, m0, v0, ws);
    main_i8<<<dim3(16, 16, 8), dim3(256), 0, stream>>>(ws, (float*)d_out);
}